// Round 1
// baseline (293.409 us; speedup 1.0000x reference)
//
#include <hip/hip_runtime.h>

#define BINS 10

// ---------------------------------------------------------------------------
// ws layout: float loss_sum[10] at byte 0; unsigned counts[10] at byte 64.
// ws is poisoned 0xAA before every replay -> must zero it each launch.
// ---------------------------------------------------------------------------

__global__ void ghm_zero_ws(unsigned* ws) {
    if (threadIdx.x < 32) ws[threadIdx.x] = 0u;   // zero first 128 B
}

__device__ __forceinline__ void ghm_process(float o0, float o1, int t,
                                            float* lsum, unsigned* cnt) {
    // d = logit(target) - logit(other). valid (g < 1) <=> d > 0.
    float d = (t != 0) ? (o1 - o0) : (o0 - o1);
    if (d > 0.0f) {
        float em = __expf(-d);                 // in (0,1)
        float g  = 2.0f * em / (1.0f + em);    // in (0,1)
        int bin  = (int)(g * 10.0f);
        if (bin > BINS - 1) bin = BINS - 1;
        float loss = log1pf(em);               // -log p_t, stable (d>0)
        #pragma unroll
        for (int b = 0; b < BINS; ++b) {
            bool h = (bin == b);
            lsum[b] += h ? loss : 0.0f;
            cnt[b]  += h ? 1u : 0u;
        }
    }
}

__launch_bounds__(256, 4)
__global__ void ghm_main(const float* __restrict__ outs,   // [n,2]
                         const int*   __restrict__ tgt,    // [n]
                         float*       __restrict__ ws_lsum,
                         unsigned*    __restrict__ ws_cnt,
                         int n) {
    float    lsum[BINS];
    unsigned cnt[BINS];
    #pragma unroll
    for (int b = 0; b < BINS; ++b) { lsum[b] = 0.0f; cnt[b] = 0u; }

    int gid      = blockIdx.x * blockDim.x + threadIdx.x;
    int nthreads = gridDim.x * blockDim.x;
    int npacks   = n >> 2;                     // 4 samples per pack

    const float4* outs4 = (const float4*)outs; // 2 float4 per pack
    const int4*   tgt4  = (const int4*)tgt;

    for (int p = gid; p < npacks; p += nthreads) {
        float4 oa = outs4[2 * p];
        float4 ob = outs4[2 * p + 1];
        int4   tt = tgt4[p];
        ghm_process(oa.x, oa.y, tt.x, lsum, cnt);
        ghm_process(oa.z, oa.w, tt.y, lsum, cnt);
        ghm_process(ob.x, ob.y, tt.z, lsum, cnt);
        ghm_process(ob.z, ob.w, tt.w, lsum, cnt);
    }
    // scalar tail (n % 4)
    int tail = n & 3;
    if (gid < tail) {
        int s = (npacks << 2) + gid;
        ghm_process(outs[2 * s], outs[2 * s + 1], tgt[s], lsum, cnt);
    }

    // block reduction via LDS atomics, then 20 global atomics per block
    __shared__ float    s_lsum[BINS];
    __shared__ unsigned s_cnt[BINS];
    if (threadIdx.x < BINS) { s_lsum[threadIdx.x] = 0.0f; s_cnt[threadIdx.x] = 0u; }
    __syncthreads();
    #pragma unroll
    for (int b = 0; b < BINS; ++b) {
        if (cnt[b]) {
            atomicAdd(&s_lsum[b], lsum[b]);
            atomicAdd(&s_cnt[b],  cnt[b]);
        }
    }
    __syncthreads();
    if (threadIdx.x < BINS) {
        if (s_cnt[threadIdx.x]) {
            atomicAdd(&ws_lsum[threadIdx.x], s_lsum[threadIdx.x]);
            atomicAdd(&ws_cnt[threadIdx.x],  s_cnt[threadIdx.x]);
        }
    }
}

__global__ void ghm_final(const float*    __restrict__ ws_lsum,
                          const unsigned* __restrict__ ws_cnt,
                          const float*    __restrict__ acc_sum,
                          float* __restrict__ out) {
    if (threadIdx.x == 0) {
        float r = 0.0f;
        #pragma unroll
        for (int b = 0; b < BINS; ++b) {
            unsigned c = ws_cnt[b];
            if (c > 0u) {
                float na = 0.75f * acc_sum[b] + 0.25f * (float)c;
                r += ws_lsum[b] / na;   // = (1/N) * sum(loss_i * N/na[bin_i])
            }
        }
        *out = r;
    }
}

extern "C" void kernel_launch(void* const* d_in, const int* in_sizes, int n_in,
                              void* d_out, int out_size, void* d_ws, size_t ws_size,
                              hipStream_t stream) {
    const float* outputs = (const float*)d_in[0];  // [N,2] f32
    const int*   targets = (const int*)d_in[1];    // [N] int
    const float* acc_sum = (const float*)d_in[2];  // [10] f32
    int n = in_sizes[1];

    float*    ws_lsum = (float*)d_ws;
    unsigned* ws_cnt  = (unsigned*)((char*)d_ws + 64);

    ghm_zero_ws<<<1, 64, 0, stream>>>((unsigned*)d_ws);
    ghm_main<<<1024, 256, 0, stream>>>(outputs, targets, ws_lsum, ws_cnt, n);
    ghm_final<<<1, 64, 0, stream>>>(ws_lsum, ws_cnt, acc_sum, (float*)d_out);
}

// Round 2
// 244.678 us; speedup vs baseline: 1.1992x; 1.1992x over previous
//
#include <hip/hip_runtime.h>

#define BINS 10

// ws layout: float loss_sum[10] @ byte 0; unsigned counts[10] @ byte 64.
// ws is re-poisoned 0xAA before every replay -> zero it each launch.

__global__ void ghm_zero_ws(unsigned* ws) {
    if (threadIdx.x < 32) ws[threadIdx.x] = 0u;   // zero first 128 B
}

__global__ __launch_bounds__(256, 8)
void ghm_main(const float* __restrict__ outs,   // [n,2]
              const int*   __restrict__ tgt,    // [n]
              float*       __restrict__ ws_lsum,
              unsigned*    __restrict__ ws_cnt,
              int n) {
    // Per-thread-column LDS histograms: column tid is private to thread tid.
    // addr = (b*256+tid)*4 -> bank = tid%32 -> 2-way aliasing (free on gfx950).
    __shared__ float    h_lsum[BINS][256];   // 10 KB
    __shared__ unsigned h_cnt [BINS][256];   // 10 KB

    const int tid = threadIdx.x;
    #pragma unroll
    for (int b = 0; b < BINS; ++b) { h_lsum[b][tid] = 0.0f; h_cnt[b][tid] = 0u; }
    __syncthreads();

    const int gid      = blockIdx.x * blockDim.x + tid;
    const int nthreads = gridDim.x * blockDim.x;
    const int npacks   = n >> 2;

    const float4* outs4 = (const float4*)outs;  // 2 float4 per 4-sample pack
    const int4*   tgt4  = (const int4*)tgt;

    for (int p = gid; p < npacks; p += nthreads) {
        float4 oa = outs4[2 * p];
        float4 ob = outs4[2 * p + 1];
        int4   tt = tgt4[p];

        float s0 = oa.x - oa.y, s1 = oa.z - oa.w;
        float s2 = ob.x - ob.y, s3 = ob.z - ob.w;
        float d0 = __int_as_float(__float_as_int(s0) ^ (tt.x << 31));
        float d1 = __int_as_float(__float_as_int(s1) ^ (tt.y << 31));
        float d2 = __int_as_float(__float_as_int(s2) ^ (tt.z << 31));
        float d3 = __int_as_float(__float_as_int(s3) ^ (tt.w << 31));

        #pragma unroll
        for (int k = 0; k < 4; ++k) {
            float d = (k == 0) ? d0 : (k == 1) ? d1 : (k == 2) ? d2 : d3;
            if (d > 0.0f) {                       // valid (g < 1) <=> d > 0
                float em   = __expf(-d);          // v_exp_f32, em in (0,1)
                float onep = 1.0f + em;
                float r    = __builtin_amdgcn_rcpf(onep);   // v_rcp_f32
                int   bin  = (int)(20.0f * em * r);         // floor(10*g)
                bin = min(bin, BINS - 1);
                float loss = __logf(onep);        // log1p(em), em in (0,1)
                atomicAdd(&h_lsum[bin][tid], loss);   // ds_add_f32, no-return
                atomicAdd(&h_cnt [bin][tid], 1u);     // ds_add_u32, no-return
            }
        }
    }
    // tail (n % 4) — n is divisible by 4 here, kept for safety
    int tail = n & 3;
    if (gid < tail) {
        int s = (npacks << 2) + gid;
        float sv = outs[2 * s] - outs[2 * s + 1];
        float d  = __int_as_float(__float_as_int(sv) ^ (tgt[s] << 31));
        if (d > 0.0f) {
            float em   = __expf(-d);
            float onep = 1.0f + em;
            int   bin  = min((int)(20.0f * em * __builtin_amdgcn_rcpf(onep)), BINS - 1);
            atomicAdd(&h_lsum[bin][tid], __logf(onep));
            atomicAdd(&h_cnt [bin][tid], 1u);
        }
    }
    __syncthreads();

    // Block reduction: each wave shuffle-reduces its 64 columns per bin.
    const int lane = tid & 63;
    const int wv   = tid >> 6;                    // 4 waves per block
    float    wl[BINS];
    unsigned wc[BINS];
    #pragma unroll
    for (int b = 0; b < BINS; ++b) {
        float    v = h_lsum[b][tid];
        unsigned c = h_cnt [b][tid];
        #pragma unroll
        for (int m = 32; m > 0; m >>= 1) {
            v += __shfl_xor(v, m);
            c += __shfl_xor(c, m);
        }
        wl[b] = v; wc[b] = c;
    }
    __syncthreads();                              // histogram reads all done

    // Reuse histogram LDS for the 4-wave combine (40 floats + 40 uints).
    float*    sbuf = &h_lsum[0][0];
    unsigned* cbuf = &h_cnt [0][0];
    if (lane == 0) {
        #pragma unroll
        for (int b = 0; b < BINS; ++b) {
            sbuf[b * 4 + wv] = wl[b];
            cbuf[b * 4 + wv] = wc[b];
        }
    }
    __syncthreads();
    if (tid < BINS) {
        float    s = sbuf[tid*4] + sbuf[tid*4+1] + sbuf[tid*4+2] + sbuf[tid*4+3];
        unsigned c = cbuf[tid*4] + cbuf[tid*4+1] + cbuf[tid*4+2] + cbuf[tid*4+3];
        if (c) {
            atomicAdd(&ws_lsum[tid], s);
            atomicAdd(&ws_cnt [tid], c);
        }
    }
}

__global__ void ghm_final(const float*    __restrict__ ws_lsum,
                          const unsigned* __restrict__ ws_cnt,
                          const float*    __restrict__ acc_sum,
                          float* __restrict__ out) {
    if (threadIdx.x == 0) {
        float r = 0.0f;
        #pragma unroll
        for (int b = 0; b < BINS; ++b) {
            unsigned c = ws_cnt[b];
            if (c > 0u) {
                float na = 0.75f * acc_sum[b] + 0.25f * (float)c;
                r += ws_lsum[b] / na;   // = (1/N) * sum(loss_i * N/na[bin_i])
            }
        }
        *out = r;
    }
}

extern "C" void kernel_launch(void* const* d_in, const int* in_sizes, int n_in,
                              void* d_out, int out_size, void* d_ws, size_t ws_size,
                              hipStream_t stream) {
    const float* outputs = (const float*)d_in[0];  // [N,2] f32
    const int*   targets = (const int*)d_in[1];    // [N] int32
    const float* acc_sum = (const float*)d_in[2];  // [10] f32
    int n = in_sizes[1];

    float*    ws_lsum = (float*)d_ws;
    unsigned* ws_cnt  = (unsigned*)((char*)d_ws + 64);

    ghm_zero_ws<<<1, 64, 0, stream>>>((unsigned*)d_ws);
    // 20 KB LDS/block -> 8 blocks/CU; 2048 blocks fills 256 CUs at 32 waves/CU.
    ghm_main<<<2048, 256, 0, stream>>>(outputs, targets, ws_lsum, ws_cnt, n);
    ghm_final<<<1, 64, 0, stream>>>(ws_lsum, ws_cnt, acc_sum, (float*)d_out);
}

// Round 3
// 241.704 us; speedup vs baseline: 1.2139x; 1.0123x over previous
//
#include <hip/hip_runtime.h>

#define BINS   10
#define ROWS   11            // +1 trash row for invalid (d<=0) lanes
#define CSHIFT 26
#define QMASK  0x03FFFFFFu   // low 26 bits: quantized loss sum
#define QSCALE 2097152.0f    // 2^21; loss <= ln2 -> q <= 1.46M; 32/sample-col sums < 2^26

// ws layout: float loss_sum[10] @ byte 0; unsigned counts[10] @ byte 64.
// ws re-poisoned 0xAA before every replay -> zero each launch.

__global__ void ghm_zero_ws(unsigned* ws) {
    if (threadIdx.x < 32) ws[threadIdx.x] = 0u;
}

__device__ __forceinline__ void proc1(float o0, float o1, int t,
                                      unsigned (*h)[256], int tid) {
    float s  = o0 - o1;
    float d  = __int_as_float(__float_as_int(s) ^ (t << 31)); // target-minus-other
    float em = __expf(-d);                         // valid lanes: em in (0,1)
    float onep = 1.0f + em;
    float r  = __builtin_amdgcn_rcpf(onep);
    int bin  = (int)(20.0f * em * r);              // floor(10*g), g = 2em/(1+em)
    bin = min(bin, BINS - 1);
    bin = (d > 0.0f) ? bin : BINS;                 // invalid -> trash row (no branch)
    float loss = __logf(onep);                     // log1p(em), stable for d>0
    unsigned q = (unsigned)(fmaf(loss, QSCALE, 0.5f));  // round-to-nearest quantize
    atomicAdd(&h[bin][tid], (1u << CSHIFT) + q);   // single ds_add_u32, no-return
}

__device__ __forceinline__ void proc4(float4 a, float4 b, int4 t,
                                      unsigned (*h)[256], int tid) {
    proc1(a.x, a.y, t.x, h, tid);
    proc1(a.z, a.w, t.y, h, tid);
    proc1(b.x, b.y, t.z, h, tid);
    proc1(b.z, b.w, t.w, h, tid);
}

__global__ __launch_bounds__(256, 4)
void ghm_main(const float* __restrict__ outs,   // [n,2]
              const int*   __restrict__ tgt,    // [n]
              float*       __restrict__ ws_lsum,
              unsigned*    __restrict__ ws_cnt,
              int n) {
    // Per-thread-column packed histograms; addr bank = tid%32 -> 2-way (free).
    __shared__ unsigned h[ROWS][256];              // 11 KB
    __shared__ unsigned s_c[BINS][16];
    __shared__ float    s_q[BINS][16];

    const int tid = threadIdx.x;
    #pragma unroll
    for (int r2 = 0; r2 < ROWS; ++r2) h[r2][tid] = 0u;
    __syncthreads();

    const int gid      = blockIdx.x * blockDim.x + tid;
    const int nthreads = gridDim.x * blockDim.x;
    const int npacks   = n >> 2;                   // 4 samples per pack

    const float4* outs4 = (const float4*)outs;
    const int4*   tgt4  = (const int4*)tgt;

    // 2 packs (8 samples) per iteration: 6 dwordx4 loads in flight
    int p = gid;
    for (; p + nthreads < npacks; p += 2 * nthreads) {
        int p2 = p + nthreads;
        float4 a0 = outs4[2 * p];
        float4 a1 = outs4[2 * p + 1];
        int4   t0 = tgt4[p];
        float4 b0 = outs4[2 * p2];
        float4 b1 = outs4[2 * p2 + 1];
        int4   t1 = tgt4[p2];
        proc4(a0, a1, t0, h, tid);
        proc4(b0, b1, t1, h, tid);
    }
    for (; p < npacks; p += nthreads) {            // cleanup (odd iteration count)
        float4 a0 = outs4[2 * p];
        float4 a1 = outs4[2 * p + 1];
        int4   t0 = tgt4[p];
        proc4(a0, a1, t0, h, tid);
    }
    int tail = n & 3;                              // scalar tail (n%4; 0 here)
    if (gid < tail) {
        int s = (npacks << 2) + gid;
        proc1(outs[2 * s], outs[2 * s + 1], tgt[s], h, tid);
    }
    __syncthreads();

    // Epilogue: no shuffles. 160 threads each unpack+sum 16 columns of one bin.
    if (tid < 16 * BINS) {
        int bin  = tid >> 4;
        int part = tid & 15;
        unsigned c = 0, qs = 0;
        #pragma unroll
        for (int j = 0; j < 16; ++j) {             // col = j*16+part: 4-way bank, tiny
            unsigned v = h[bin][j * 16 + part];
            c  += v >> CSHIFT;
            qs += v & QMASK;
        }
        s_c[bin][part] = c;
        s_q[bin][part] = (float)qs;
    }
    __syncthreads();
    if (tid < BINS) {
        unsigned c = 0; float q = 0.0f;
        #pragma unroll
        for (int j = 0; j < 16; ++j) { c += s_c[tid][j]; q += s_q[tid][j]; }
        if (c) {
            atomicAdd(&ws_cnt[tid],  c);
            atomicAdd(&ws_lsum[tid], q * (1.0f / QSCALE));
        }
    }
}

__global__ void ghm_final(const float*    __restrict__ ws_lsum,
                          const unsigned* __restrict__ ws_cnt,
                          const float*    __restrict__ acc_sum,
                          float* __restrict__ out) {
    if (threadIdx.x == 0) {
        float r = 0.0f;
        #pragma unroll
        for (int b = 0; b < BINS; ++b) {
            unsigned c = ws_cnt[b];
            if (c > 0u) {
                float na = 0.75f * acc_sum[b] + 0.25f * (float)c;
                r += ws_lsum[b] / na;   // = (1/N) * sum(loss_i * N/na[bin_i])
            }
        }
        *out = r;
    }
}

extern "C" void kernel_launch(void* const* d_in, const int* in_sizes, int n_in,
                              void* d_out, int out_size, void* d_ws, size_t ws_size,
                              hipStream_t stream) {
    const float* outputs = (const float*)d_in[0];  // [N,2] f32
    const int*   targets = (const int*)d_in[1];    // [N] int32
    const float* acc_sum = (const float*)d_in[2];  // [10] f32
    int n = in_sizes[1];

    float*    ws_lsum = (float*)d_ws;
    unsigned* ws_cnt  = (unsigned*)((char*)d_ws + 64);

    ghm_zero_ws<<<1, 64, 0, stream>>>((unsigned*)d_ws);
    // 12.5 KB LDS/block; 2048 blocks -> 8 blocks/CU, 32 waves/CU.
    ghm_main<<<2048, 256, 0, stream>>>(outputs, targets, ws_lsum, ws_cnt, n);
    ghm_final<<<1, 64, 0, stream>>>(ws_lsum, ws_cnt, acc_sum, (float*)d_out);
}